// Round 1
// baseline (28556.647 us; speedup 1.0000x reference)
//
#include <hip/hip_runtime.h>

// ---------------- problem constants ----------------
constexpr int Bsz  = 1024;           // batch
constexpr int Tn   = 200;            // T
constexpr int TS   = Tn - 1;         // 199 steps
constexpr int Dd   = 64;             // D
constexpr int Hh   = 512;            // H
constexpr int OUTd = 64;             // OUT
constexpr int CST  = TS * 4 * Dd;    // coeffs row stride per b = 50944 floats
constexpr int OST  = Tn * OUTd;      // out row stride per b = 12800 floats
constexpr int KIN  = Hh + Dd;        // packed input-GEMM K = 576

// ---------------- helpers ----------------
__device__ __forceinline__ float lips(float v) {
  // 0.909 * silu(v) = 0.909 * v * sigmoid(v)
  return 0.909f * (v / (1.0f + expf(-v)));
}

__device__ __forceinline__ void fma16(float (&acc)[4][4], const float4 av, const float4 bv) {
  const float aa[4] = {av.x, av.y, av.z, av.w};
  const float bb[4] = {bv.x, bv.y, bv.z, bv.w};
#pragma unroll
  for (int i = 0; i < 4; ++i)
#pragma unroll
    for (int j = 0; j < 4; ++j)
      acc[i][j] = fmaf(aa[i], bb[j], acc[i][j]);
}

// ---------------- Levy increments: dL[t*B + b] ----------------
__global__ void levy_k(const float* __restrict__ U, const float* __restrict__ E,
                       float* __restrict__ dL) {
  const int i = blockIdx.x * 256 + threadIdx.x;
  if (i >= TS * Bsz) return;
  const float u = U[i], e = E[i];
  // beta = 0: const=0, phi=0, S=1
  const float num = sinf(1.9f * u);
  const float den = powf(cosf(u), (float)(1.0 / 1.9));
  const float fr  = powf(cosf(u - 1.9f * u) / e, (float)((1.0 - 1.9) / 1.9));
  dL[i] = num / den * fr;
}

// ---------------- pack W_in / W_noise: drop col 0, keep it separately ----------------
__global__ void pack_k(const float* __restrict__ Win, const float* __restrict__ Wno,
                       float* __restrict__ wf, float* __restrict__ wg,
                       float* __restrict__ w0f, float* __restrict__ w0g) {
  const int i = blockIdx.x * 256 + threadIdx.x;
  if (i >= Hh * KIN) return;
  const int n = i / KIN, k = i - n * KIN;
  wf[i] = Win[n * (KIN + 1) + 1 + k];
  wg[i] = Wno[n * (KIN + 1) + 1 + k];
  if (k == 0) { w0f[n] = Win[n * (KIN + 1)]; w0g[n] = Wno[n * (KIN + 1)]; }
}

// ---------------- y0 = x0 @ W_init.T + b_init  (M=1024,N=512,K=64) ----------------
__global__ __launch_bounds__(256, 2)
void y0_k(const float* __restrict__ coeffs, const float* __restrict__ Wi,
          const float* __restrict__ bi, float* __restrict__ y) {
  __shared__ __align__(16) float As[32][68];
  __shared__ __align__(16) float Bs[32][68];
  const int tid = threadIdx.x;
  const int tx = tid & 15, ty = tid >> 4;
  const int m0 = blockIdx.x << 6;
  const int n0 = blockIdx.y << 6;
  const int r = tid >> 3, k4 = (tid & 7) << 2;
  float acc[4][4] = {};
  for (int c = 0; c < 2; ++c) {
    const int k0 = c << 5;
    const float4 a0 = *reinterpret_cast<const float4*>(coeffs + (size_t)(m0 + r) * CST + k0 + k4);
    const float4 a1 = *reinterpret_cast<const float4*>(coeffs + (size_t)(m0 + r + 32) * CST + k0 + k4);
    const float4 b0 = *reinterpret_cast<const float4*>(Wi + (size_t)(n0 + r) * 64 + k0 + k4);
    const float4 b1 = *reinterpret_cast<const float4*>(Wi + (size_t)(n0 + r + 32) * 64 + k0 + k4);
    As[k4+0][r] = a0.x; As[k4+1][r] = a0.y; As[k4+2][r] = a0.z; As[k4+3][r] = a0.w;
    As[k4+0][r+32] = a1.x; As[k4+1][r+32] = a1.y; As[k4+2][r+32] = a1.z; As[k4+3][r+32] = a1.w;
    Bs[k4+0][r] = b0.x; Bs[k4+1][r] = b0.y; Bs[k4+2][r] = b0.z; Bs[k4+3][r] = b0.w;
    Bs[k4+0][r+32] = b1.x; Bs[k4+1][r+32] = b1.y; Bs[k4+2][r+32] = b1.z; Bs[k4+3][r+32] = b1.w;
    __syncthreads();
#pragma unroll
    for (int k = 0; k < 32; ++k) {
      const float4 av = *reinterpret_cast<const float4*>(&As[k][ty << 2]);
      const float4 bv = *reinterpret_cast<const float4*>(&Bs[k][tx << 2]);
      fma16(acc, av, bv);
    }
    __syncthreads();
  }
  const int nn = n0 + (tx << 2);
#pragma unroll
  for (int i = 0; i < 4; ++i) {
    const int gm = m0 + (ty << 2) + i;
    float4 rg;
    rg.x = acc[i][0] + bi[nn + 0];
    rg.y = acc[i][1] + bi[nn + 1];
    rg.z = acc[i][2] + bi[nn + 2];
    rg.w = acc[i][3] + bi[nn + 3];
    *reinterpret_cast<float4*>(y + (size_t)gm * Hh + nn) = rg;
  }
}

// ---------------- input GEMM + fused decode of current y ----------------
// grid (16, 17): bn<16 -> h0 tiles (K=576 over [y|x_t], both paths);
//                bn==16 -> decode tile out[:,t,:] = y @ Wdec.T + bdec (K=512)
__global__ __launch_bounds__(256, 2)
void in_k(const float* __restrict__ y, const float* __restrict__ coeffs,
          const float* __restrict__ wf, const float* __restrict__ wg,
          const float* __restrict__ bf, const float* __restrict__ bg,
          const float* __restrict__ w0f, const float* __restrict__ w0g,
          const float* __restrict__ Wd, const float* __restrict__ bd,
          const float* __restrict__ times, int t,
          float* __restrict__ h0, float* __restrict__ out) {
  __shared__ __align__(16) float As[32][68];
  __shared__ __align__(16) float Bs[32][68];
  const int tid = threadIdx.x;
  const int tx = tid & 15, ty = tid >> 4;
  const int bm = blockIdx.x, bn = blockIdx.y;
  const int m0 = bm << 6;
  const bool dec = (bn == 16);
  const int path = dec ? 0 : (bn >> 3);
  const int n0 = dec ? 0 : ((bn & 7) << 6);
  const float* Wp = dec ? Wd : (path ? wg : wf);
  const int ldb = dec ? Hh : KIN;
  const int NC = dec ? 16 : 18;
  const int r = tid >> 3, k4 = (tid & 7) << 2;

  auto ldA = [&](int row, int k) -> float4 {
    if (k < Hh)
      return *reinterpret_cast<const float4*>(y + (size_t)(m0 + row) * Hh + k);
    return *reinterpret_cast<const float4*>(coeffs + (size_t)(m0 + row) * CST + t * 256 + (k - Hh));
  };

  float4 a0 = ldA(r, k4);
  float4 a1 = ldA(r + 32, k4);
  float4 b0 = *reinterpret_cast<const float4*>(Wp + (size_t)(n0 + r) * ldb + k4);
  float4 b1 = *reinterpret_cast<const float4*>(Wp + (size_t)(n0 + r + 32) * ldb + k4);
  float acc[4][4] = {};
  for (int c = 0; c < NC; ++c) {
    As[k4+0][r] = a0.x; As[k4+1][r] = a0.y; As[k4+2][r] = a0.z; As[k4+3][r] = a0.w;
    As[k4+0][r+32] = a1.x; As[k4+1][r+32] = a1.y; As[k4+2][r+32] = a1.z; As[k4+3][r+32] = a1.w;
    Bs[k4+0][r] = b0.x; Bs[k4+1][r] = b0.y; Bs[k4+2][r] = b0.z; Bs[k4+3][r] = b0.w;
    Bs[k4+0][r+32] = b1.x; Bs[k4+1][r+32] = b1.y; Bs[k4+2][r+32] = b1.z; Bs[k4+3][r+32] = b1.w;
    __syncthreads();
    if (c + 1 < NC) {
      const int k0 = (c + 1) << 5;
      a0 = ldA(r, k0 + k4);
      a1 = ldA(r + 32, k0 + k4);
      b0 = *reinterpret_cast<const float4*>(Wp + (size_t)(n0 + r) * ldb + k0 + k4);
      b1 = *reinterpret_cast<const float4*>(Wp + (size_t)(n0 + r + 32) * ldb + k0 + k4);
    }
#pragma unroll
    for (int k = 0; k < 32; ++k) {
      const float4 av = *reinterpret_cast<const float4*>(&As[k][ty << 2]);
      const float4 bv = *reinterpret_cast<const float4*>(&Bs[k][tx << 2]);
      fma16(acc, av, bv);
    }
    __syncthreads();
  }
  const int nn = n0 + (tx << 2);
  if (dec) {
#pragma unroll
    for (int i = 0; i < 4; ++i) {
      const int gm = m0 + (ty << 2) + i;
      float4 rg;
      rg.x = acc[i][0] + bd[nn + 0];
      rg.y = acc[i][1] + bd[nn + 1];
      rg.z = acc[i][2] + bd[nn + 2];
      rg.w = acc[i][3] + bd[nn + 3];
      *reinterpret_cast<float4*>(out + (size_t)gm * OST + t * OUTd + nn) = rg;
    }
  } else {
    const float tv = times[t];
    const float* bias = path ? bg : bf;
    const float* w0 = path ? w0g : w0f;
#pragma unroll
    for (int i = 0; i < 4; ++i) {
      const int gm = m0 + (ty << 2) + i;
      float4 rg;
      rg.x = acc[i][0] + tv * w0[nn + 0] + bias[nn + 0];
      rg.y = acc[i][1] + tv * w0[nn + 1] + bias[nn + 1];
      rg.z = acc[i][2] + tv * w0[nn + 2] + bias[nn + 2];
      rg.w = acc[i][3] + tv * w0[nn + 3] + bias[nn + 3];
      *reinterpret_cast<float4*>(h0 + (size_t)gm * 1024 + (path << 9) + nn) = rg;
    }
  }
}

// ---------------- hidden layer GEMM for both paths (N=1024 combined) ----------------
__global__ __launch_bounds__(256, 2)
void hid_k(const float* __restrict__ hin, const float* __restrict__ Wf,
           const float* __restrict__ Wg, const float* __restrict__ bfp,
           const float* __restrict__ bgp, float* __restrict__ hout, int act) {
  __shared__ __align__(16) float As[32][68];
  __shared__ __align__(16) float Bs[32][68];
  const int tid = threadIdx.x;
  const int tx = tid & 15, ty = tid >> 4;
  const int m0 = blockIdx.x << 6;
  const int bn = blockIdx.y;
  const int path = bn >> 3;
  const int n0 = (bn & 7) << 6;
  const float* W = path ? Wg : Wf;
  const float* bias = path ? bgp : bfp;
  const float* Ab = hin + (size_t)m0 * 1024 + (path << 9);
  const int r = tid >> 3, k4 = (tid & 7) << 2;

  float4 a0 = *reinterpret_cast<const float4*>(Ab + (size_t)r * 1024 + k4);
  float4 a1 = *reinterpret_cast<const float4*>(Ab + (size_t)(r + 32) * 1024 + k4);
  float4 b0 = *reinterpret_cast<const float4*>(W + (size_t)(n0 + r) * Hh + k4);
  float4 b1 = *reinterpret_cast<const float4*>(W + (size_t)(n0 + r + 32) * Hh + k4);
  float acc[4][4] = {};
  for (int c = 0; c < 16; ++c) {
    As[k4+0][r] = a0.x; As[k4+1][r] = a0.y; As[k4+2][r] = a0.z; As[k4+3][r] = a0.w;
    As[k4+0][r+32] = a1.x; As[k4+1][r+32] = a1.y; As[k4+2][r+32] = a1.z; As[k4+3][r+32] = a1.w;
    Bs[k4+0][r] = b0.x; Bs[k4+1][r] = b0.y; Bs[k4+2][r] = b0.z; Bs[k4+3][r] = b0.w;
    Bs[k4+0][r+32] = b1.x; Bs[k4+1][r+32] = b1.y; Bs[k4+2][r+32] = b1.z; Bs[k4+3][r+32] = b1.w;
    __syncthreads();
    if (c < 15) {
      const int k0 = (c + 1) << 5;
      a0 = *reinterpret_cast<const float4*>(Ab + (size_t)r * 1024 + k0 + k4);
      a1 = *reinterpret_cast<const float4*>(Ab + (size_t)(r + 32) * 1024 + k0 + k4);
      b0 = *reinterpret_cast<const float4*>(W + (size_t)(n0 + r) * Hh + k0 + k4);
      b1 = *reinterpret_cast<const float4*>(W + (size_t)(n0 + r + 32) * Hh + k0 + k4);
    }
#pragma unroll
    for (int k = 0; k < 32; ++k) {
      const float4 av = *reinterpret_cast<const float4*>(&As[k][ty << 2]);
      const float4 bv = *reinterpret_cast<const float4*>(&Bs[k][tx << 2]);
      fma16(acc, av, bv);
    }
    __syncthreads();
  }
  const int nn = n0 + (tx << 2);
#pragma unroll
  for (int i = 0; i < 4; ++i) {
    const int gm = m0 + (ty << 2) + i;
    float v0 = acc[i][0] + bias[nn + 0];
    float v1 = acc[i][1] + bias[nn + 1];
    float v2 = acc[i][2] + bias[nn + 2];
    float v3 = acc[i][3] + bias[nn + 3];
    if (act) { v0 = lips(v0); v1 = lips(v1); v2 = lips(v2); v3 = lips(v3); }
    const float4 rg = {v0, v1, v2, v3};
    *reinterpret_cast<float4*>(hout + (size_t)gm * 1024 + (path << 9) + nn) = rg;
  }
}

// ---------------- y += drift*dt + jump*dL ----------------
__global__ void upd_k(float* __restrict__ y, const float* __restrict__ hraw,
                      const float* __restrict__ dL, const float* __restrict__ times, int t) {
  const int i = blockIdx.x * 256 + threadIdx.x;   // 131072 float4s exactly
  const int b = i >> 7, c4 = (i & 127) << 2;
  const float dt = times[t + 1] - times[t];
  const float dl = dL[t * Bsz + b];
  const float4 dr = *reinterpret_cast<const float4*>(hraw + (size_t)b * 1024 + c4);
  const float4 jp = *reinterpret_cast<const float4*>(hraw + (size_t)b * 1024 + Hh + c4);
  float4 v = *reinterpret_cast<float4*>(y + (size_t)b * Hh + c4);
  v.x += dr.x * dt + jp.x * dl;
  v.y += dr.y * dt + jp.y * dl;
  v.z += dr.z * dt + jp.z * dl;
  v.w += dr.w * dt + jp.w * dl;
  *reinterpret_cast<float4*>(y + (size_t)b * Hh + c4) = v;
}

// ---------------- final decode out[:,199,:] ----------------
__global__ __launch_bounds__(256, 2)
void dec_k(const float* __restrict__ y, const float* __restrict__ Wd,
           const float* __restrict__ bd, float* __restrict__ out) {
  __shared__ __align__(16) float As[32][68];
  __shared__ __align__(16) float Bs[32][68];
  const int tid = threadIdx.x;
  const int tx = tid & 15, ty = tid >> 4;
  const int m0 = blockIdx.x << 6;
  const int r = tid >> 3, k4 = (tid & 7) << 2;
  float4 a0 = *reinterpret_cast<const float4*>(y + (size_t)(m0 + r) * Hh + k4);
  float4 a1 = *reinterpret_cast<const float4*>(y + (size_t)(m0 + r + 32) * Hh + k4);
  float4 b0 = *reinterpret_cast<const float4*>(Wd + (size_t)r * Hh + k4);
  float4 b1 = *reinterpret_cast<const float4*>(Wd + (size_t)(r + 32) * Hh + k4);
  float acc[4][4] = {};
  for (int c = 0; c < 16; ++c) {
    As[k4+0][r] = a0.x; As[k4+1][r] = a0.y; As[k4+2][r] = a0.z; As[k4+3][r] = a0.w;
    As[k4+0][r+32] = a1.x; As[k4+1][r+32] = a1.y; As[k4+2][r+32] = a1.z; As[k4+3][r+32] = a1.w;
    Bs[k4+0][r] = b0.x; Bs[k4+1][r] = b0.y; Bs[k4+2][r] = b0.z; Bs[k4+3][r] = b0.w;
    Bs[k4+0][r+32] = b1.x; Bs[k4+1][r+32] = b1.y; Bs[k4+2][r+32] = b1.z; Bs[k4+3][r+32] = b1.w;
    __syncthreads();
    if (c < 15) {
      const int k0 = (c + 1) << 5;
      a0 = *reinterpret_cast<const float4*>(y + (size_t)(m0 + r) * Hh + k0 + k4);
      a1 = *reinterpret_cast<const float4*>(y + (size_t)(m0 + r + 32) * Hh + k0 + k4);
      b0 = *reinterpret_cast<const float4*>(Wd + (size_t)r * Hh + k0 + k4);
      b1 = *reinterpret_cast<const float4*>(Wd + (size_t)(r + 32) * Hh + k0 + k4);
    }
#pragma unroll
    for (int k = 0; k < 32; ++k) {
      const float4 av = *reinterpret_cast<const float4*>(&As[k][ty << 2]);
      const float4 bv = *reinterpret_cast<const float4*>(&Bs[k][tx << 2]);
      fma16(acc, av, bv);
    }
    __syncthreads();
  }
  const int nn = tx << 2;
#pragma unroll
  for (int i = 0; i < 4; ++i) {
    const int gm = m0 + (ty << 2) + i;
    float4 rg;
    rg.x = acc[i][0] + bd[nn + 0];
    rg.y = acc[i][1] + bd[nn + 1];
    rg.z = acc[i][2] + bd[nn + 2];
    rg.w = acc[i][3] + bd[nn + 3];
    *reinterpret_cast<float4*>(out + (size_t)gm * OST + (Tn - 1) * OUTd + nn) = rg;
  }
}

// ---------------- launch ----------------
extern "C" void kernel_launch(void* const* d_in, const int* in_sizes, int n_in,
                              void* d_out, int out_size, void* d_ws, size_t ws_size,
                              hipStream_t stream) {
  const float* coeffs = (const float*)d_in[0];
  const float* times  = (const float*)d_in[1];
  const float* W_in   = (const float*)d_in[2];
  const float* b_in   = (const float*)d_in[3];
  const float* f_W    = (const float*)d_in[4];
  const float* f_b    = (const float*)d_in[5];
  const float* W_no   = (const float*)d_in[6];
  const float* b_no   = (const float*)d_in[7];
  const float* g_W    = (const float*)d_in[8];
  const float* g_b    = (const float*)d_in[9];
  const float* W_init = (const float*)d_in[10];
  const float* b_init = (const float*)d_in[11];
  const float* W_dec  = (const float*)d_in[12];
  const float* b_dec  = (const float*)d_in[13];
  const float* U      = (const float*)d_in[14];
  const float* E      = (const float*)d_in[15];
  float* out = (float*)d_out;

  float* ws  = (float*)d_ws;
  float* y   = ws;                          // 1024*512
  float* hA  = y  + (size_t)Bsz * Hh;       // 1024*1024
  float* hB  = hA + (size_t)Bsz * 2 * Hh;   // 1024*1024
  float* dL  = hB + (size_t)Bsz * 2 * Hh;   // 199*1024
  float* wf  = dL + (size_t)TS * Bsz;       // 512*576
  float* wg  = wf + (size_t)Hh * KIN;       // 512*576
  float* w0f = wg + (size_t)Hh * KIN;       // 512
  float* w0g = w0f + Hh;                    // 512

  levy_k<<<(TS * Bsz + 255) / 256, 256, 0, stream>>>(U, E, dL);
  pack_k<<<(Hh * KIN + 255) / 256, 256, 0, stream>>>(W_in, W_no, wf, wg, w0f, w0g);
  y0_k<<<dim3(16, 8), 256, 0, stream>>>(coeffs, W_init, b_init, y);

  constexpr int LW = Hh * Hh;   // 262144 per layer
  for (int t = 0; t < TS; ++t) {
    in_k<<<dim3(16, 17), 256, 0, stream>>>(y, coeffs, wf, wg, b_in, b_no, w0f, w0g,
                                           W_dec, b_dec, times, t, hA, out);
    hid_k<<<dim3(16, 16), 256, 0, stream>>>(hA, f_W,          g_W,          f_b,           g_b,           hB, 1);
    hid_k<<<dim3(16, 16), 256, 0, stream>>>(hB, f_W + LW,     g_W + LW,     f_b + Hh,      g_b + Hh,      hA, 1);
    hid_k<<<dim3(16, 16), 256, 0, stream>>>(hA, f_W + 2 * LW, g_W + 2 * LW, f_b + 2 * Hh,  g_b + 2 * Hh,  hB, 1);
    hid_k<<<dim3(16, 16), 256, 0, stream>>>(hB, f_W + 3 * LW, g_W + 3 * LW, f_b + 3 * Hh,  g_b + 3 * Hh,  hA, 0);
    upd_k<<<512, 256, 0, stream>>>(y, hA, dL, times, t);
  }
  dec_k<<<dim3(16, 1), 256, 0, stream>>>(y, W_dec, b_dec, out);
}

// Round 2
// 13231.746 us; speedup vs baseline: 2.1582x; 2.1582x over previous
//
#include <hip/hip_runtime.h>

typedef _Float16 f16;
typedef __attribute__((ext_vector_type(8))) _Float16 f16x8;
typedef __attribute__((ext_vector_type(4))) float floatx4;
typedef __attribute__((ext_vector_type(4))) unsigned int uintx4;

constexpr int Bsz  = 1024;
constexpr int Tn   = 200;
constexpr int TS   = Tn - 1;          // 199
constexpr int Dd   = 64;
constexpr int Hh   = 512;
constexpr int OUTd = 64;
constexpr int CST  = TS * 4 * Dd;     // 50944 floats per batch row of coeffs
constexpr int OST  = Tn * OUTd;       // 12800 floats per batch row of out
constexpr int KIN  = 576;             // packed input-GEMM K (t column folded out)
constexpr int NIN  = 1088;            // f(512) | g(512) | dec(64)

__device__ __forceinline__ float lips(float v) {
  return 0.909f * (v / (1.0f + expf(-v)));
}

// ---------------- Levy increments: dL[t*B + b] ----------------
__global__ void levy_k(const float* __restrict__ U, const float* __restrict__ E,
                       float* __restrict__ dL) {
  const int i = blockIdx.x * 256 + threadIdx.x;
  if (i >= TS * Bsz) return;
  const float u = U[i], e = E[i];
  // beta = 0: const=0, phi=0, S=1
  const float num = sinf(1.9f * u);
  const float den = powf(cosf(u), (float)(1.0 / 1.9));
  const float fr  = powf(cosf(u - 1.9f * u) / e, (float)((1.0 - 1.9) / 1.9));
  dL[i] = num / den * fr;
}

// ---------------- pack weights into hi/lo f16 + concat biases ----------------
// WinH/L: [1088][576]  rows: 0..511 W_in (col0 dropped), 512..1023 W_noise, 1024..1087 W_dec (K padded w/ 0)
// WhidH/L: [4][1024][512]  rows: 0..511 f_W[l], 512..1023 g_W[l]
__global__ void packw_k(const float* __restrict__ Win, const float* __restrict__ Wno,
                        const float* __restrict__ Wdec,
                        const float* __restrict__ fW, const float* __restrict__ gW,
                        const float* __restrict__ bin, const float* __restrict__ bno,
                        const float* __restrict__ fb, const float* __restrict__ gb,
                        f16* __restrict__ WiH, f16* __restrict__ WiL,
                        f16* __restrict__ WhH, f16* __restrict__ WhL,
                        float* __restrict__ w0cat, float* __restrict__ biasin,
                        float* __restrict__ bhid) {
  const int i = blockIdx.x * 256 + threadIdx.x;
  const int NW1 = NIN * KIN;                     // 626688
  if (i < NW1) {
    const int n = i / KIN, k = i - n * KIN;
    float v;
    if (n < 512)       v = Win[n * (KIN + 1) + 1 + k];
    else if (n < 1024) v = Wno[(n - 512) * (KIN + 1) + 1 + k];
    else               v = (k < 512) ? Wdec[(n - 1024) * 512 + k] : 0.0f;
    const f16 h = (f16)v;
    WiH[i] = h; WiL[i] = (f16)(v - (float)h);
  }
  const int i2 = i - NW1;                        // Whid: 4*1024*512
  if (i2 >= 0 && i2 < 4 * 1024 * 512) {
    const int l = i2 >> 19;
    const int r = i2 & 524287;
    const int n = r >> 9, k = r & 511;
    const float v = (n < 512) ? fW[((size_t)l * 512 + n) * 512 + k]
                              : gW[((size_t)l * 512 + (n - 512)) * 512 + k];
    const f16 h = (f16)v;
    WhH[i2] = h; WhL[i2] = (f16)(v - (float)h);
  }
  if (i < 1024) {
    w0cat[i]  = (i < 512) ? Win[i * (KIN + 1)] : Wno[(i - 512) * (KIN + 1)];
    biasin[i] = (i < 512) ? bin[i] : bno[i - 512];
  }
  if (i < 4096) {
    const int l = i >> 10, n = i & 1023;
    bhid[i] = (n < 512) ? fb[l * 512 + n] : gb[l * 512 + (n - 512)];
  }
}

// ---------------- y0 = x0 @ W_init.T + b_init (fp32, K=64) + split write ----------------
__global__ __launch_bounds__(256)
void y0_k(const float* __restrict__ coeffs, const float* __restrict__ Wi,
          const float* __restrict__ bi, float* __restrict__ y,
          f16* __restrict__ YH, f16* __restrict__ YL) {
  __shared__ __align__(16) float As[32][68];
  __shared__ __align__(16) float Bs[32][68];
  const int tid = threadIdx.x;
  const int tx = tid & 15, ty = tid >> 4;
  const int m0 = blockIdx.x << 6;
  const int n0 = blockIdx.y << 6;
  const int r = tid >> 3, k4 = (tid & 7) << 2;
  float acc[4][4] = {};
  for (int c = 0; c < 2; ++c) {
    const int k0 = c << 5;
    const floatx4 a0 = *reinterpret_cast<const floatx4*>(coeffs + (size_t)(m0 + r) * CST + k0 + k4);
    const floatx4 a1 = *reinterpret_cast<const floatx4*>(coeffs + (size_t)(m0 + r + 32) * CST + k0 + k4);
    const floatx4 b0 = *reinterpret_cast<const floatx4*>(Wi + (size_t)(n0 + r) * 64 + k0 + k4);
    const floatx4 b1 = *reinterpret_cast<const floatx4*>(Wi + (size_t)(n0 + r + 32) * 64 + k0 + k4);
#pragma unroll
    for (int e = 0; e < 4; ++e) {
      As[k4 + e][r] = a0[e]; As[k4 + e][r + 32] = a1[e];
      Bs[k4 + e][r] = b0[e]; Bs[k4 + e][r + 32] = b1[e];
    }
    __syncthreads();
#pragma unroll
    for (int k = 0; k < 32; ++k) {
      const floatx4 av = *reinterpret_cast<const floatx4*>(&As[k][ty << 2]);
      const floatx4 bv = *reinterpret_cast<const floatx4*>(&Bs[k][tx << 2]);
#pragma unroll
      for (int ii = 0; ii < 4; ++ii)
#pragma unroll
        for (int jj = 0; jj < 4; ++jj)
          acc[ii][jj] = fmaf(av[ii], bv[jj], acc[ii][jj]);
    }
    __syncthreads();
  }
  const int nn = n0 + (tx << 2);
#pragma unroll
  for (int ii = 0; ii < 4; ++ii) {
    const int gm = m0 + (ty << 2) + ii;
#pragma unroll
    for (int jj = 0; jj < 4; ++jj) {
      const float v = acc[ii][jj] + bi[nn + jj];
      y[(size_t)gm * Hh + nn + jj] = v;
      const f16 h = (f16)v;
      YH[(size_t)gm * Hh + nn + jj] = h;
      YL[(size_t)gm * Hh + nn + jj] = (f16)(v - (float)h);
    }
  }
}

// ---------------- split-f16 MFMA GEMM ----------------
// 64x64 block tile, 4 waves (32x32 each), BK=64, double-buffered LDS.
// LDS octet swizzle: (row, koct) stored at j = koct ^ (row&7)  (rows stride 128B).
// modes: 0 = hidden w/ lipswish -> split out; 1 = last hidden -> fp32 hraw;
//        2 = input GEMM (NC=9, x chunk, dec tile at bn==16); 3 = final decode (NC=8, dec only)
__global__ __launch_bounds__(256)
void mf_k(const f16* __restrict__ Ah, const f16* __restrict__ Al, int Ast,
          const f16* __restrict__ Wh, const f16* __restrict__ Wl, int Wst,
          int NC, int mode, int t,
          const float* __restrict__ coeffs, const float* __restrict__ times,
          const float* __restrict__ biasin, const float* __restrict__ w0cat,
          const float* __restrict__ bhid_l, const float* __restrict__ bdec,
          f16* __restrict__ OutH, f16* __restrict__ OutL,
          float* __restrict__ hraw, float* __restrict__ out) {
  __shared__ f16 smem[2][4][4096];        // [buf][Ah,Al,Bh,Bl][64 rows x 64 k]
  const int tid = threadIdx.x;
  const int l = tid & 63, w = tid >> 6;
  const int wm = w >> 1, wn = w & 1;
  const int m0 = blockIdx.x << 6;
  const int bn = blockIdx.y;
  const int n0 = (mode == 3) ? 1024 : (bn << 6);
  const bool dec = (mode == 3) || (mode == 2 && bn == 16);
  const int aoff = ((mode == 0 || mode == 1) && n0 >= 512) ? 512 : 0;

  // staging geometry: instr i covers rows 8i..8i+7; lane -> (row, koct)
  const int srow = l >> 3, skoct = l & 7;
  const f16* sb;
  int sst;
  if (w < 2) { sb = (w == 0 ? Ah : Al) + (size_t)m0 * Ast + aoff; sst = Ast; }
  else       { sb = (w == 2 ? Wh : Wl) + (size_t)n0 * Wst;        sst = Wst; }

  uintx4 sreg[8];
  auto prefetch = [&](int c) {
#pragma unroll
    for (int i = 0; i < 8; ++i) {
      const int row = i * 8 + srow;
      sreg[i] = *reinterpret_cast<const uintx4*>(sb + (size_t)row * sst + c * 64 + skoct * 8);
    }
  };

  // frag row indices (per lane)
  const int c15 = l & 15, hi4 = l >> 4;
  int rA[2], rB[2];
  rA[0] = wm * 32 + c15;      rA[1] = rA[0] + 16;
  rB[0] = wn * 32 + c15;      rB[1] = rB[0] + 16;

  floatx4 acc[2][2] = {};

  prefetch(0);
  for (int c = 0; c < NC; ++c) {
    f16* dst = &smem[c & 1][w][0];
    if (mode == 2 && c == 8 && w < 2) {
      // x chunk: convert coeffs fp32 -> hi/lo octets on the fly
#pragma unroll
      for (int i = 0; i < 8; ++i) {
        const int row = i * 8 + srow;
        const float* xs = coeffs + (size_t)(m0 + row) * CST + t * 256 + skoct * 8;
        const floatx4 v0 = *reinterpret_cast<const floatx4*>(xs);
        const floatx4 v1 = *reinterpret_cast<const floatx4*>(xs + 4);
        f16x8 o;
#pragma unroll
        for (int e = 0; e < 4; ++e) {
          const f16 h0 = (f16)v0[e], h1 = (f16)v1[e];
          o[e]     = (w == 0) ? h0 : (f16)(v0[e] - (float)h0);
          o[e + 4] = (w == 0) ? h1 : (f16)(v1[e] - (float)h1);
        }
        const int j = skoct ^ (row & 7);
        *reinterpret_cast<f16x8*>(dst + row * 64 + j * 8) = o;
      }
    } else {
#pragma unroll
      for (int i = 0; i < 8; ++i) {
        const int row = i * 8 + srow;
        const int j = skoct ^ (row & 7);
        *reinterpret_cast<uintx4*>(dst + row * 64 + j * 8) = sreg[i];
      }
    }
    if (c + 1 < NC && !(mode == 2 && c + 1 == 8 && w < 2)) prefetch(c + 1);
    __syncthreads();

    const f16* AH = &smem[c & 1][0][0];
    const f16* AL = &smem[c & 1][1][0];
    const f16* BH = &smem[c & 1][2][0];
    const f16* BL = &smem[c & 1][3][0];
#pragma unroll
    for (int s = 0; s < 2; ++s) {
      const int ko = s * 4 + hi4;
      f16x8 ah[2], al2[2], bh[2], bl[2];
#pragma unroll
      for (int q = 0; q < 2; ++q) {
        const int ja = ko ^ (rA[q] & 7);
        ah[q]  = *reinterpret_cast<const f16x8*>(AH + rA[q] * 64 + ja * 8);
        al2[q] = *reinterpret_cast<const f16x8*>(AL + rA[q] * 64 + ja * 8);
        const int jb = ko ^ (rB[q] & 7);
        bh[q]  = *reinterpret_cast<const f16x8*>(BH + rB[q] * 64 + jb * 8);
        bl[q]  = *reinterpret_cast<const f16x8*>(BL + rB[q] * 64 + jb * 8);
      }
#pragma unroll
      for (int q = 0; q < 2; ++q)
#pragma unroll
        for (int p = 0; p < 2; ++p) {
          acc[q][p] = __builtin_amdgcn_mfma_f32_16x16x32_f16(ah[q],  bh[p], acc[q][p], 0, 0, 0);
          acc[q][p] = __builtin_amdgcn_mfma_f32_16x16x32_f16(al2[q], bh[p], acc[q][p], 0, 0, 0);
          acc[q][p] = __builtin_amdgcn_mfma_f32_16x16x32_f16(ah[q],  bl[p], acc[q][p], 0, 0, 0);
        }
    }
    if (c + 1 < NC) __syncthreads();
  }

  // ---------------- epilogue ----------------
  const float tv = (mode == 2) ? times[t] : 0.0f;
#pragma unroll
  for (int q = 0; q < 2; ++q) {
#pragma unroll
    for (int p = 0; p < 2; ++p) {
      const int nloc = wn * 32 + p * 16 + c15;
      const int n = n0 + nloc;
#pragma unroll
      for (int r = 0; r < 4; ++r) {
        const int m = m0 + wm * 32 + q * 16 + hi4 * 4 + r;
        float v = acc[q][p][r];
        if (mode == 0) {
          v = lips(v + bhid_l[n]);
          const f16 h = (f16)v;
          OutH[(size_t)m * 1024 + n] = h;
          OutL[(size_t)m * 1024 + n] = (f16)(v - (float)h);
        } else if (mode == 1) {
          hraw[(size_t)m * 1024 + n] = v + bhid_l[n];
        } else if (!dec) {
          v += biasin[n] + tv * w0cat[n];
          const f16 h = (f16)v;
          OutH[(size_t)m * 1024 + n] = h;
          OutL[(size_t)m * 1024 + n] = (f16)(v - (float)h);
        } else {
          out[(size_t)m * OST + t * OUTd + nloc] = v + bdec[nloc];
        }
      }
    }
  }
}

// ---------------- y += drift*dt + jump*dL, write y + split ----------------
__global__ void upd_k(float* __restrict__ y, f16* __restrict__ YH, f16* __restrict__ YL,
                      const float* __restrict__ hraw, const float* __restrict__ dL,
                      const float* __restrict__ times, int t) {
  const int i = blockIdx.x * 256 + threadIdx.x;   // 131072 float4s
  const int b = i >> 7, c4 = (i & 127) << 2;
  const float dt = times[t + 1] - times[t];
  const float dl = dL[t * Bsz + b];
  const floatx4 dr = *reinterpret_cast<const floatx4*>(hraw + (size_t)b * 1024 + c4);
  const floatx4 jp = *reinterpret_cast<const floatx4*>(hraw + (size_t)b * 1024 + 512 + c4);
  floatx4 v = *reinterpret_cast<floatx4*>(y + (size_t)b * Hh + c4);
#pragma unroll
  for (int e = 0; e < 4; ++e) v[e] += dr[e] * dt + jp[e] * dl;
  *reinterpret_cast<floatx4*>(y + (size_t)b * Hh + c4) = v;
  f16* yh = YH + (size_t)b * Hh + c4;
  f16* yl = YL + (size_t)b * Hh + c4;
#pragma unroll
  for (int e = 0; e < 4; ++e) {
    const f16 h = (f16)v[e];
    yh[e] = h; yl[e] = (f16)(v[e] - (float)h);
  }
}

// ---------------- launch ----------------
extern "C" void kernel_launch(void* const* d_in, const int* in_sizes, int n_in,
                              void* d_out, int out_size, void* d_ws, size_t ws_size,
                              hipStream_t stream) {
  const float* coeffs = (const float*)d_in[0];
  const float* times  = (const float*)d_in[1];
  const float* W_in   = (const float*)d_in[2];
  const float* b_in   = (const float*)d_in[3];
  const float* f_W    = (const float*)d_in[4];
  const float* f_b    = (const float*)d_in[5];
  const float* W_no   = (const float*)d_in[6];
  const float* b_no   = (const float*)d_in[7];
  const float* g_W    = (const float*)d_in[8];
  const float* g_b    = (const float*)d_in[9];
  const float* W_init = (const float*)d_in[10];
  const float* b_init = (const float*)d_in[11];
  const float* W_dec  = (const float*)d_in[12];
  const float* b_dec  = (const float*)d_in[13];
  const float* U      = (const float*)d_in[14];
  const float* E      = (const float*)d_in[15];
  float* out = (float*)d_out;

  // workspace layout
  float* dL    = (float*)d_ws;                       // 199*1024
  float* y     = dL + TS * Bsz;                      // 1024*512
  float* w0c   = y + (size_t)Bsz * Hh;               // 1024
  float* bic   = w0c + 1024;                         // 1024
  float* bhid  = bic + 1024;                         // 4*1024
  f16* YH  = (f16*)(bhid + 4096);                    // 1024*512
  f16* YL  = YH + (size_t)Bsz * Hh;
  f16* hAH = YL + (size_t)Bsz * Hh;                  // 1024*1024 each
  f16* hAL = hAH + (size_t)Bsz * 1024;
  f16* hBH = hAL + (size_t)Bsz * 1024;
  f16* hBL = hBH + (size_t)Bsz * 1024;
  f16* WiH = hBL + (size_t)Bsz * 1024;               // 1088*576
  f16* WiL = WiH + (size_t)NIN * KIN;
  f16* WhH = WiL + (size_t)NIN * KIN;                // 4*1024*512
  f16* WhL = WhH + (size_t)4 * 1024 * 512;
  float* hraw = (float*)hAH;                         // alias: live only hid4 -> upd

  levy_k<<<(TS * Bsz + 255) / 256, 256, 0, stream>>>(U, E, dL);
  {
    const int total = NIN * KIN + 4 * 1024 * 512;
    packw_k<<<(total + 255) / 256, 256, 0, stream>>>(W_in, W_no, W_dec, f_W, g_W,
                                                     b_in, b_no, f_b, g_b,
                                                     WiH, WiL, WhH, WhL, w0c, bic, bhid);
  }
  y0_k<<<dim3(16, 8), 256, 0, stream>>>(coeffs, W_init, b_init, y, YH, YL);

  constexpr size_t LW = 1024 * 512;
  for (int t = 0; t < TS; ++t) {
    // input GEMM + decode of y_t (N = 1088)
    mf_k<<<dim3(16, 17), 256, 0, stream>>>(YH, YL, Hh, WiH, WiL, KIN, 9, 2, t,
                                           coeffs, times, bic, w0c, nullptr, b_dec,
                                           hAH, hAL, nullptr, out);
    // hidden layers (f|g fused in N)
    mf_k<<<dim3(16, 16), 256, 0, stream>>>(hAH, hAL, 1024, WhH, WhL, Hh, 8, 0, t,
                                           nullptr, times, nullptr, nullptr, bhid, nullptr,
                                           hBH, hBL, nullptr, nullptr);
    mf_k<<<dim3(16, 16), 256, 0, stream>>>(hBH, hBL, 1024, WhH + LW, WhL + LW, Hh, 8, 0, t,
                                           nullptr, times, nullptr, nullptr, bhid + 1024, nullptr,
                                           hAH, hAL, nullptr, nullptr);
    mf_k<<<dim3(16, 16), 256, 0, stream>>>(hAH, hAL, 1024, WhH + 2 * LW, WhL + 2 * LW, Hh, 8, 0, t,
                                           nullptr, times, nullptr, nullptr, bhid + 2048, nullptr,
                                           hBH, hBL, nullptr, nullptr);
    // last hidden: raw fp32 (drift | jump) -> hraw (aliases hA region)
    mf_k<<<dim3(16, 16), 256, 0, stream>>>(hBH, hBL, 1024, WhH + 3 * LW, WhL + 3 * LW, Hh, 8, 1, t,
                                           nullptr, times, nullptr, nullptr, bhid + 3072, nullptr,
                                           nullptr, nullptr, hraw, nullptr);
    upd_k<<<512, 256, 0, stream>>>(y, YH, YL, hraw, dL, times, t);
  }
  // final decode of y_199 (K=512 only)
  mf_k<<<dim3(16, 1), 256, 0, stream>>>(YH, YL, Hh, WiH, WiL, KIN, 8, 3, TS,
                                        nullptr, times, nullptr, nullptr, nullptr, b_dec,
                                        nullptr, nullptr, nullptr, out);
}